// Round 4
// baseline (160.023 us; speedup 1.0000x reference)
//
#include <hip/hip_runtime.h>
#include <math.h>

#define N1 16384
#define N2 16384
#define BLOCK 256
#define COLS 16                         // pos1 columns
#define SLICES 64                       // pos2 slices
#define PTS 4                           // pos1 points per thread (COLS*BLOCK*PTS = N1)
#define COL_PTS (BLOCK * PTS)           // 1024 points per column
#define SLICE_F4 ((N2 / SLICES) / 2)    // 128 float4 per slice (256 points)
// grid = COLS x SLICES = 1024 blocks = 4 blocks/CU

// Single fused kernel, NO cooperative launch (graph-capture kills it; round-3
// lesson). Cross-block ordering via the round-0-proven device-scope
// atomicAdd-ticket + __threadfence election.
// Phase 1: block (col, sl) computes, for its 1024 pos1 points,
//   min over slice sl of g(q) = -2 p.q + |q|^2   (d^2 = |p|^2 + g)
//   and plain-stores the per-slice minima (no atomics, no big memset).
// Election: last block of each column (ticket[col] == SLICES-1) reduces the
//   column's 64 slices (256 KB, L2-hot), adds |p|^2, sqrt, block-sums.
// Final: last of the 16 finishers (ticket[COLS]) reduces 16 sums -> mean.
__global__ __launch_bounds__(BLOCK, 4)
void nn_fused(const float2* __restrict__ pos1,
              const float4* __restrict__ pos2,    // 2 points per float4
              float* __restrict__ partials,       // [SLICES][N1]
              float* __restrict__ blocksums,      // [COLS]
              unsigned int* __restrict__ tickets, // [COLS+1], memset to 0
              float* __restrict__ out) {
    const int col = blockIdx.x;
    const int sl  = blockIdx.y;
    const int t   = threadIdx.x;

    // ---------------- phase 1: one slice partial ----------------
    const float4* __restrict__ q = pos2 + (size_t)sl * SLICE_F4;
    const int i0 = col * COL_PTS + t;

    float x[PTS], y[PTS], m[PTS];
#pragma unroll
    for (int k = 0; k < PTS; ++k) {
        float2 p = pos1[i0 + k * BLOCK];
        x[k] = -2.f * p.x;   // fold -2 into p (exact)
        y[k] = -2.f * p.y;
        m[k] = 3.4e38f;
    }

#pragma unroll 4
    for (int j = 0; j < SLICE_F4; ++j) {
        float4 qq = q[j];                          // uniform address, 2 pos2 pts
        float az = fmaf(qq.x, qq.x, qq.y * qq.y);  // |qa|^2
        float bz = fmaf(qq.z, qq.z, qq.w * qq.w);  // |qb|^2
#pragma unroll
        for (int k = 0; k < PTS; ++k) {
            float ta = fmaf(x[k], qq.x, fmaf(y[k], qq.y, az));
            float tb = fmaf(x[k], qq.z, fmaf(y[k], qq.w, bz));
            m[k] = fminf(m[k], fminf(ta, tb));     // -> v_min3_f32
        }
    }

    float* dst = partials + (size_t)sl * N1 + i0;
#pragma unroll
    for (int k = 0; k < PTS; ++k) {
        dst[k * BLOCK] = m[k];                     // coalesced across t
    }

    // ---------------- election (round-0-proven pattern) ----------------
    __threadfence();                               // release partials
    __shared__ int rank;
    if (t == 0) rank = (int)atomicAdd(&tickets[col], 1u);
    __syncthreads();
    if (rank != SLICES - 1) return;                // losers exit
    __threadfence();                               // acquire partials

    // ---------------- phase 2: column finish ----------------
    float g[PTS];
#pragma unroll
    for (int k = 0; k < PTS; ++k) g[k] = 3.4e38f;

#pragma unroll 4
    for (int s2 = 0; s2 < SLICES; ++s2) {          // coalesced across t, L2-hot
        const float* src = partials + (size_t)s2 * N1 + i0;
#pragma unroll
        for (int k = 0; k < PTS; ++k) {
            g[k] = fminf(g[k], src[k * BLOCK]);
        }
    }

    float sum = 0.f;
#pragma unroll
    for (int k = 0; k < PTS; ++k) {
        float2 p = pos1[i0 + k * BLOCK];
        float d2 = fmaxf(fmaf(p.x, p.x, p.y * p.y) + g[k], 0.f);
        sum += sqrtf(d2);
    }

    for (int off = 32; off > 0; off >>= 1) {
        sum += __shfl_down(sum, off, 64);
    }
    __shared__ float wsum[BLOCK / 64];
    __shared__ int lastflag;
    if ((t & 63) == 0) wsum[t >> 6] = sum;
    __syncthreads();
    if (t == 0) {
        float s = 0.f;
        for (int w = 0; w < BLOCK / 64; ++w) s += wsum[w];
        blocksums[col] = s;
        __threadfence();
        unsigned int old = atomicAdd(&tickets[COLS], 1u);
        lastflag = (old == COLS - 1) ? 1 : 0;
    }
    __syncthreads();
    if (lastflag && t < 64) {
        __threadfence();
        volatile float* vb = (volatile float*)blocksums;
        float v = (t < COLS) ? vb[t] : 0.f;
        for (int off = 32; off > 0; off >>= 1) {
            v += __shfl_down(v, off, 64);
        }
        if (t == 0) out[0] = v / (float)N1;
    }
}

extern "C" void kernel_launch(void* const* d_in, const int* in_sizes, int n_in,
                              void* d_out, int out_size, void* d_ws, size_t ws_size,
                              hipStream_t stream) {
    const float2* pos1 = (const float2*)d_in[0];
    const float4* pos2 = (const float4*)d_in[1];
    float* out = (float*)d_out;

    float* partials       = (float*)d_ws;                    // [64][16384] = 4 MB
    float* blocksums      = partials + (size_t)SLICES * N1;  // 16 floats
    unsigned int* tickets = (unsigned int*)(blocksums + COLS); // COLS+1 uints

    // init tickets only (68 B) -- workspace is poisoned every iteration
    hipMemsetAsync(tickets, 0, (COLS + 1) * sizeof(unsigned int), stream);

    dim3 grid(COLS, SLICES);
    nn_fused<<<grid, BLOCK, 0, stream>>>(pos1, pos2, partials, blocksums,
                                         tickets, out);
}

// Round 5
// 84.606 us; speedup vs baseline: 1.8914x; 1.8914x over previous
//
#include <hip/hip_runtime.h>
#include <math.h>

#define N1 16384
#define N2 16384
#define BLOCK 256
#define PTS 8                          // pos1 points per thread
#define I_BLOCKS (N1 / (BLOCK * PTS))  // 8 columns
#define SLICES 128                     // pos2 slices -> grid 8x128 = 1024 blocks
#define SLICE_F4 ((N2 / SLICES) / 2)   // 64 float4 per slice

// order-preserving float<->uint mapping (for atomicMin over possibly-negative g)
__device__ __forceinline__ unsigned int f2key(float f) {
    unsigned int b = __float_as_uint(f);
    return (b & 0x80000000u) ? ~b : (b | 0x80000000u);
}
__device__ __forceinline__ float key2f(unsigned int k) {
    unsigned int b = (k & 0x80000000u) ? (k & 0x7FFFFFFFu) : ~k;
    return __uint_as_float(b);
}

// Single fused kernel. ALL cross-block handoff via device-coherent ops only:
// atomicMin/atomicAdd, relaxed-agent __hip_atomic_load/store (sc1, bypass
// local L1/L2), vmcnt(0) drains, and one acquire (invalidate-only) fence.
// NO __threadfence in the wide part: round-4 post-mortem showed threadfence's
// buffer_wbl2 (full L2 writeback) x1024 blocks forced 4 MB through HBM and
// cost 106 us. Plain-store handoff needs wbl2; atomic handoff does not.
//
// Phase 1 (all 1024 blocks): round-2-proven math. For each of 2048 pos1
//   points per column, min over one pos2 slice of g(q) = -2 p.q + |q|^2
//   (d^2 = |p|^2 + g), combined across slices by atomicMin on 64 KB keys.
// Election per column: drain own atomics (vmcnt), relaxed ticket atomicAdd;
//   tickets init 0xFFFFFFFF by the same memset as keys -> last of 128
//   arrivals sees old == 126 (the "-1 trick").
// Phase 2 (8 winner blocks): acquire-inv fence, coherent-load keys, decode,
//   + |p|^2, sqrt, block-sum; coherent-store blocksum, final ticket; last of
//   8 reduces and writes the mean.
__global__ __launch_bounds__(BLOCK, 4)
void nn_fused(const float2* __restrict__ pos1,
              const float4* __restrict__ pos2,     // 2 points per float4
              unsigned int* __restrict__ keys,     // [N1], memset 0xFF
              unsigned int* __restrict__ tickets,  // [I_BLOCKS+1], memset 0xFF
              float* __restrict__ blocksums,       // [I_BLOCKS], no init needed
              float* __restrict__ out) {
    const int ib = blockIdx.x;
    const int sl = blockIdx.y;
    const int t  = threadIdx.x;
    const int i0 = ib * (BLOCK * PTS) + t;

    // ---------------- phase 1 ----------------
    const float4* __restrict__ q = pos2 + (size_t)sl * SLICE_F4;

    float x[PTS], y[PTS], m[PTS];
#pragma unroll
    for (int k = 0; k < PTS; ++k) {
        float2 p = pos1[i0 + k * BLOCK];
        x[k] = -2.f * p.x;   // fold -2 into p (exact)
        y[k] = -2.f * p.y;
        m[k] = 3.4e38f;
    }

#pragma unroll 4
    for (int j = 0; j < SLICE_F4; ++j) {
        float4 qq = q[j];                          // uniform address, 2 pos2 pts
        float az = fmaf(qq.x, qq.x, qq.y * qq.y);  // |qa|^2
        float bz = fmaf(qq.z, qq.z, qq.w * qq.w);  // |qb|^2
#pragma unroll
        for (int k = 0; k < PTS; ++k) {
            float ta = fmaf(x[k], qq.x, fmaf(y[k], qq.y, az));
            float tb = fmaf(x[k], qq.z, fmaf(y[k], qq.w, bz));
            m[k] = fminf(m[k], fminf(ta, tb));     // -> v_min3_f32
        }
    }

#pragma unroll
    for (int k = 0; k < PTS; ++k) {
        atomicMin(&keys[i0 + k * BLOCK], f2key(m[k]));  // device-coherent
    }

    // ---------------- election (coherent ops only, no wbl2) ----------------
    asm volatile("s_waitcnt vmcnt(0)" ::: "memory");  // my atomics performed
    __shared__ int rank;
    if (t == 0) rank = (int)atomicAdd(&tickets[ib], 1u);
    __syncthreads();
    if (rank != SLICES - 2) return;   // init -1: last of 128 sees 126

    // invalidate stale local L1/L2 copies (no writeback -> cheap)
    __builtin_amdgcn_fence(__ATOMIC_ACQUIRE, "agent");

    // ---------------- phase 2: column finish (8 blocks) ----------------
    float sum = 0.f;
#pragma unroll
    for (int k = 0; k < PTS; ++k) {
        unsigned int kk = __hip_atomic_load(&keys[i0 + k * BLOCK],
                                            __ATOMIC_RELAXED,
                                            __HIP_MEMORY_SCOPE_AGENT);
        float g = key2f(kk);
        float2 p = pos1[i0 + k * BLOCK];
        float d2 = fmaxf(fmaf(p.x, p.x, p.y * p.y) + g, 0.f);
        sum += sqrtf(d2);
    }

    for (int off = 32; off > 0; off >>= 1) {
        sum += __shfl_down(sum, off, 64);
    }
    __shared__ float wsum[BLOCK / 64];
    __shared__ int lastflag;
    if ((t & 63) == 0) wsum[t >> 6] = sum;
    __syncthreads();
    if (t == 0) {
        float s = 0.f;
        for (int w = 0; w < BLOCK / 64; ++w) s += wsum[w];
        __hip_atomic_store(&blocksums[ib], s, __ATOMIC_RELAXED,
                           __HIP_MEMORY_SCOPE_AGENT);       // sc1 write-through
        asm volatile("s_waitcnt vmcnt(0)" ::: "memory");    // store performed
        unsigned int old = atomicAdd(&tickets[I_BLOCKS], 1u);
        lastflag = (old == (unsigned)(I_BLOCKS - 2)) ? 1 : 0; // last of 8 sees 6
    }
    __syncthreads();
    if (lastflag && t < 64) {
        float v = (t < I_BLOCKS)
            ? __hip_atomic_load(&blocksums[t], __ATOMIC_RELAXED,
                                __HIP_MEMORY_SCOPE_AGENT)
            : 0.f;
        for (int off = 4; off > 0; off >>= 1) {
            v += __shfl_down(v, off, 64);
        }
        if (t == 0) out[0] = v / (float)N1;
    }
}

extern "C" void kernel_launch(void* const* d_in, const int* in_sizes, int n_in,
                              void* d_out, int out_size, void* d_ws, size_t ws_size,
                              hipStream_t stream) {
    const float2* pos1 = (const float2*)d_in[0];
    const float4* pos2 = (const float4*)d_in[1];
    float* out = (float*)d_out;

    unsigned int* keys    = (unsigned int*)d_ws;            // N1 uints (64 KB)
    unsigned int* tickets = keys + N1;                      // I_BLOCKS+1 uints
    float* blocksums      = (float*)(tickets + I_BLOCKS + 1); // 8 floats

    // one memset covers keys (+inf ordering) AND tickets (-1 trick): 0xFF
    hipMemsetAsync(keys, 0xFF, (size_t)(N1 + I_BLOCKS + 1) * sizeof(unsigned int),
                   stream);

    dim3 grid(I_BLOCKS, SLICES);
    nn_fused<<<grid, BLOCK, 0, stream>>>(pos1, pos2, keys, tickets, blocksums, out);
}

// Round 6
// 80.908 us; speedup vs baseline: 1.9778x; 1.0457x over previous
//
#include <hip/hip_runtime.h>
#include <math.h>

#define N1 16384
#define N2 16384
#define BLOCK 512                      // phase-1 block: 8 waves
#define PTS 4                          // pos1 points per thread
#define I_BLOCKS (N1 / (BLOCK * PTS))  // 8 columns
#define SLICES 128                     // pos2 slices -> grid 8x128 = 1024 blocks
                                       // = 4 blocks/CU x 8 waves = 32 waves/CU
#define SLICE_F4 ((N2 / SLICES) / 2)   // 64 float4 per slice
#define FBLOCK 256                     // finish block (proven R0 shape)

// order-preserving float<->uint mapping (for atomicMin over possibly-negative g)
__device__ __forceinline__ unsigned int f2key(float f) {
    unsigned int b = __float_as_uint(f);
    return (b & 0x80000000u) ? ~b : (b | 0x80000000u);
}
__device__ __forceinline__ float key2f(unsigned int k) {
    unsigned int b = (k & 0x80000000u) ? (k & 0x7FFFFFFFu) : ~k;
    return __uint_as_float(b);
}

// Stage 1: for each pos1 point, min over one pos2 slice of
// g(q) = -2 p.q + |q|^2  (d^2 = |p|^2 + g, shift applied in stage 2).
// R5 post-mortem: phase 1 is latency-bound (VALUBusy ~20%, instr shave was
// neutral), so this round doubles resident waves: BLOCK=512/PTS=4 keeps the
// grid at 1024 blocks but runs 32 waves/CU (was 16). atomicMin count
// unchanged at 2.1M (threads x2, PTS /2). Fire-and-forget combine (proven).
__global__ __launch_bounds__(BLOCK, 8)
void nn_partial(const float2* __restrict__ pos1,
                const float4* __restrict__ pos2,   // 2 points per float4
                unsigned int* __restrict__ keys,
                unsigned int* __restrict__ ticket,
                int slice_f4) {
    const int ib = blockIdx.x;
    const int sl = blockIdx.y;
    const int t  = threadIdx.x;

    if (ib == 0 && sl == 0 && t == 0) *ticket = 0;  // init for stage 2

    const float4* __restrict__ q = pos2 + (size_t)sl * slice_f4;
    const int i0 = ib * (BLOCK * PTS) + t;

    float x[PTS], y[PTS], m[PTS];
#pragma unroll
    for (int k = 0; k < PTS; ++k) {
        float2 p = pos1[i0 + k * BLOCK];
        x[k] = -2.f * p.x;   // fold -2 into p (exact)
        y[k] = -2.f * p.y;
        m[k] = 3.4e38f;
    }

#pragma unroll 4
    for (int j = 0; j < slice_f4; ++j) {
        float4 qq = q[j];                          // uniform address, 2 pos2 pts
        float az = fmaf(qq.x, qq.x, qq.y * qq.y);  // |qa|^2
        float bz = fmaf(qq.z, qq.z, qq.w * qq.w);  // |qb|^2
#pragma unroll
        for (int k = 0; k < PTS; ++k) {
            float ta = fmaf(x[k], qq.x, fmaf(y[k], qq.y, az));
            float tb = fmaf(x[k], qq.z, fmaf(y[k], qq.w, bz));
            m[k] = fminf(m[k], fminf(ta, tb));     // -> v_min3_f32
        }
    }

#pragma unroll
    for (int k = 0; k < PTS; ++k) {
        atomicMin(&keys[i0 + k * BLOCK], f2key(m[k]));  // fire-and-forget
    }
}

// Stage 2 (fused final): 64 blocks; decode key, + |p|^2, sqrt, block-sum;
// last block (ticket) reduces the 64 block sums and writes the mean.
__global__ __launch_bounds__(FBLOCK)
void nn_finish(const unsigned int* __restrict__ keys,
               const float2* __restrict__ pos1,
               float* __restrict__ blocksums,
               unsigned int* __restrict__ ticket,
               float* __restrict__ out) {
    const int t = threadIdx.x;
    const int i = blockIdx.x * FBLOCK + t;

    float g = key2f(keys[i]);
    float2 p = pos1[i];
    float d2 = fmaxf(fmaf(p.x, p.x, p.y * p.y) + g, 0.f);
    float sum = sqrtf(d2);

    for (int off = 32; off > 0; off >>= 1) {
        sum += __shfl_down(sum, off, 64);
    }
    __shared__ float wsum[FBLOCK / 64];
    __shared__ int lastflag;
    if ((t & 63) == 0) wsum[t >> 6] = sum;
    __syncthreads();
    if (t == 0) {
        float s = 0.f;
        for (int w = 0; w < FBLOCK / 64; ++w) s += wsum[w];
        blocksums[blockIdx.x] = s;
        __threadfence();
        unsigned int old = atomicAdd(ticket, 1u);
        lastflag = (old == gridDim.x - 1) ? 1 : 0;
    }
    __syncthreads();
    if (lastflag && t < 64) {
        volatile float* vb = (volatile float*)blocksums;
        float v = vb[t];
        for (int off = 32; off > 0; off >>= 1) {
            v += __shfl_down(v, off, 64);
        }
        if (t == 0) out[0] = v / (float)N1;
    }
}

extern "C" void kernel_launch(void* const* d_in, const int* in_sizes, int n_in,
                              void* d_out, int out_size, void* d_ws, size_t ws_size,
                              hipStream_t stream) {
    const float2* pos1 = (const float2*)d_in[0];
    const float4* pos2 = (const float4*)d_in[1];
    float* out = (float*)d_out;

    unsigned int* keys = (unsigned int*)d_ws;               // N1 uints (64 KB)
    float* blocksums   = (float*)(keys + N1);               // 64 floats
    unsigned int* ticket = (unsigned int*)(blocksums + 64); // 1 uint

    const int slice_f4 = (N2 / SLICES) / 2;  // float4s per slice (64)

    // init keys to +inf ordering (0xFFFFFFFF)
    hipMemsetAsync(keys, 0xFF, (size_t)N1 * sizeof(unsigned int), stream);

    dim3 grid1(I_BLOCKS, SLICES);
    nn_partial<<<grid1, BLOCK, 0, stream>>>(pos1, pos2, keys, ticket, slice_f4);
    nn_finish<<<N1 / FBLOCK, FBLOCK, 0, stream>>>(keys, pos1, blocksums, ticket, out);
}